// Round 1
// baseline (85.405 us; speedup 1.0000x reference)
//
#include <hip/hip_runtime.h>

// h_t = f_t * h_{t-1} + (1 - f_t) * z_t over [T, B, H], scan along T.
// One thread per (b,h) channel: coalesced across channels at each t,
// deep rotating-register prefetch to hide HBM latency at 2 waves/CU.

constexpr int T_STEPS = 1024;
constexpr int UNROLL  = 16;   // prefetch depth (iterations in flight)

__global__ __launch_bounds__(64) void fm_scan(const float* __restrict__ f,
                                              const float* __restrict__ z,
                                              float* __restrict__ h,
                                              int BH) {
    const int ch = blockIdx.x * blockDim.x + threadIdx.x;
    if (ch >= BH) return;

    const float* fp = f + ch;
    const float* zp = z + ch;
    float*       hp = h + ch;
    const size_t stride = (size_t)BH;

    // Prefetch registers — all indexing compile-time constant after unroll
    // (runtime-indexed arrays would go to scratch).
    float pf[UNROLL], pz[UNROLL];
#pragma unroll
    for (int i = 0; i < UNROLL; ++i) {
        pf[i] = fp[(size_t)i * stride];
        pz[i] = zp[(size_t)i * stride];
    }

    float hv = 0.0f;
    int t = 0;
    for (; t < T_STEPS - UNROLL; t += UNROLL) {
#pragma unroll
        for (int i = 0; i < UNROLL; ++i) {
            const float fv = pf[i];
            const float zv = pz[i];
            // issue next-stage prefetch before the dependent math
            pf[i] = fp[(size_t)(t + UNROLL + i) * stride];
            pz[i] = zp[(size_t)(t + UNROLL + i) * stride];
            // h = f*h + (1-f)*z  ==  f*(h - z) + z   (1 sub + 1 fma)
            hv = fv * (hv - zv) + zv;
            hp[(size_t)(t + i) * stride] = hv;
        }
    }
    // epilogue: consume last UNROLL stages, no prefetch
#pragma unroll
    for (int i = 0; i < UNROLL; ++i) {
        const float fv = pf[i];
        const float zv = pz[i];
        hv = fv * (hv - zv) + zv;
        hp[(size_t)(t + i) * stride] = hv;
    }
}

extern "C" void kernel_launch(void* const* d_in, const int* in_sizes, int n_in,
                              void* d_out, int out_size, void* d_ws, size_t ws_size,
                              hipStream_t stream) {
    const float* f = (const float*)d_in[0];
    const float* z = (const float*)d_in[1];
    float*       h = (float*)d_out;

    const int BH = in_sizes[0] / T_STEPS;   // 32*1024 = 32768 channels

    const int block = 64;
    const int grid  = (BH + block - 1) / block;  // 512 blocks -> ~2 waves/CU
    fm_scan<<<grid, block, 0, stream>>>(f, z, h, BH);
}

// Round 2
// 78.097 us; speedup vs baseline: 1.0936x; 1.0936x over previous
//
#include <hip/hip_runtime.h>

// h_t = f_t * h_{t-1} + (1 - f_t) * z_t over [T=1024, B, H], scan along T.
// One thread per (b,h) channel (coalesced across channels at each t).
// Latency hiding via batch-phased ping-pong register double-buffer:
// load 16 steps (32 loads back-to-back, pinned by sched_barrier) while
// computing the previous 16. Structural occupancy is 2 waves/CU, so all
// latency hiding is MLP within the wave.

constexpr int T_STEPS = 1024;
constexpr int BATCH   = 16;   // time steps per register batch

__global__ __launch_bounds__(64) void fm_scan(const float* __restrict__ f,
                                              const float* __restrict__ z,
                                              float* __restrict__ h,
                                              int BH) {
    const int ch = blockIdx.x * blockDim.x + threadIdx.x;
    if (ch >= BH) return;

    const float* fp = f + ch;
    const float* zp = z + ch;
    float*       hp = h + ch;
    const size_t stride = (size_t)BH;

    float fA[BATCH], zA[BATCH], fB[BATCH], zB[BATCH];

    // Prologue: load batch A (t = 0..BATCH-1)
#pragma unroll
    for (int i = 0; i < BATCH; ++i) {
        fA[i] = fp[(size_t)i * stride];
        zA[i] = zp[(size_t)i * stride];
    }
    __builtin_amdgcn_sched_barrier(0);

    float hv = 0.0f;

    for (int t0 = 0; t0 < T_STEPS; t0 += 2 * BATCH) {
        // ---- Phase 1: load batch B (t0+BATCH), compute batch A (t0) ----
        if (t0 + BATCH < T_STEPS) {
#pragma unroll
            for (int i = 0; i < BATCH; ++i) {
                fB[i] = fp[(size_t)(t0 + BATCH + i) * stride];
                zB[i] = zp[(size_t)(t0 + BATCH + i) * stride];
            }
        }
        __builtin_amdgcn_sched_barrier(0);
#pragma unroll
        for (int i = 0; i < BATCH; ++i) {
            // h = f*h + (1-f)*z  ==  f*(h - z) + z
            hv = fA[i] * (hv - zA[i]) + zA[i];
            hp[(size_t)(t0 + i) * stride] = hv;
        }
        __builtin_amdgcn_sched_barrier(0);

        // ---- Phase 2: load batch A (t0+2*BATCH), compute batch B ----
        if (t0 + 2 * BATCH < T_STEPS) {
#pragma unroll
            for (int i = 0; i < BATCH; ++i) {
                fA[i] = fp[(size_t)(t0 + 2 * BATCH + i) * stride];
                zA[i] = zp[(size_t)(t0 + 2 * BATCH + i) * stride];
            }
        }
        __builtin_amdgcn_sched_barrier(0);
        if (t0 + BATCH < T_STEPS) {
#pragma unroll
            for (int i = 0; i < BATCH; ++i) {
                hv = fB[i] * (hv - zB[i]) + zB[i];
                hp[(size_t)(t0 + BATCH + i) * stride] = hv;
            }
        }
        __builtin_amdgcn_sched_barrier(0);
    }
}

extern "C" void kernel_launch(void* const* d_in, const int* in_sizes, int n_in,
                              void* d_out, int out_size, void* d_ws, size_t ws_size,
                              hipStream_t stream) {
    const float* f = (const float*)d_in[0];
    const float* z = (const float*)d_in[1];
    float*       h = (float*)d_out;

    const int BH = in_sizes[0] / T_STEPS;   // 32*1024 = 32768 channels

    const int block = 64;
    const int grid  = (BH + block - 1) / block;  // 512 blocks -> 2 waves/CU
    fm_scan<<<grid, block, 0, stream>>>(f, z, h, BH);
}